// Round 2
// baseline (466.810 us; speedup 1.0000x reference)
//
#include <hip/hip_runtime.h>

// ---------------------------------------------------------------------------
// KAN 2-layer forward, round 9.
// r8 post-mortem: counted-vmcnt barrier relaxation was NULL (263us, MfmaUtil
// 28.8 unchanged) -> the stall is NOT the barrier drain; it's occupancy.
// Measured 2 waves/SIMD (22%): LDS 72KB (2 blk/CU) AND regs 96V+128A=224
// (2 waves/SIMD on 512-reg unified file) both bind. 38% of cycles issue
// nothing; MFMA floor 1242cyc/SIMD-step vs 3946 measured.
// r9 = occupancy x2: L1 n-split into BN=256 blocks (grid y=2) -> LDS 40KB,
// acc 64 AGPR; VGPR diet (base+imm-offset ds_reads, no setprio, epilogue-only
// C pointer); __launch_bounds__(256,4) -> 4 blk/CU = 4 waves/SIMD. Cost:
// act x2 for L1 (+VALU) and X fetched twice (HBM 7->14%, fine). L2 (already
// BN=256) inherits the diet + occupancy for free. Counted-vmcnt kept: with 4
// independent blocks/CU the relaxed barriers can finally overlap.
// ---------------------------------------------------------------------------

typedef short s16x8 __attribute__((ext_vector_type(8)));  // 8 bf16 = 4 VGPRs
typedef float f32x4 __attribute__((ext_vector_type(4)));

__device__ __forceinline__ void dma16(const void* g, void* l) {
  __builtin_amdgcn_global_load_lds(
      (const __attribute__((address_space(1))) unsigned int*)g,
      (__attribute__((address_space(3))) unsigned int*)l, 16, 0, 0);
}

template <int N>
__device__ __forceinline__ void wait_vm() {
  if constexpr (N == 0)      asm volatile("s_waitcnt vmcnt(0)" ::: "memory");
  else if constexpr (N == 5) asm volatile("s_waitcnt vmcnt(5)" ::: "memory");
  else if constexpr (N == 9) asm volatile("s_waitcnt vmcnt(9)" ::: "memory");
  else static_assert(N == 0, "unsupported vmcnt");
}

__device__ __forceinline__ unsigned pk2(float lo, float hi) {
  unsigned a = __float_as_uint(lo), b = __float_as_uint(hi);
  a = a + 0x7fffu + ((a >> 16) & 1u);
  b = b + 0x7fffu + ((b >> 16) & 1u);
  return __builtin_amdgcn_perm(b, a, 0x07060302u);  // {b.hi16, a.hi16}
}

__device__ __forceinline__ unsigned short f2bf(float f) {
  unsigned u = __float_as_uint(f);
  unsigned r = u + 0x7fffu + ((u >> 16) & 1u);
  return (unsigned short)(r >> 16);
}

// silu + 6 cubic B-spline bases (uniform extended grid, u = 1.5x+4.5, knots
// u=0..9; recursion ref-verified r1..r8). Packed bf16x8 [silu,b3_0..5,0].
__device__ __forceinline__ uint4 kan_act8(float x) {
  float e = __expf(-x);
  float s = x * __builtin_amdgcn_rcpf(1.0f + e);
  float u = fmaf(x, 1.5f, 4.5f);
  float d[10];
#pragma unroll
  for (int j = 0; j < 10; ++j) d[j] = u - (float)j;
  float b1[8];
#pragma unroll
  for (int j = 0; j < 8; ++j) b1[j] = fmaxf(0.0f, 1.0f - fabsf(d[j + 1]));
  float B2[7];
#pragma unroll
  for (int j = 0; j < 7; ++j) B2[j] = d[j] * b1[j] - d[j + 3] * b1[j + 1];
  float b3[6];
#pragma unroll
  for (int j = 0; j < 6; ++j)
    b3[j] = (d[j] * B2[j] - d[j + 4] * B2[j + 1]) * (1.0f / 6.0f);
  uint4 r;
  r.x = pk2(s, b3[0]);
  r.y = pk2(b3[1], b3[2]);
  r.z = pk2(b3[3], b3[4]);
  r.w = pk2(b3[5], 0.0f);
  return r;
}

// Pack weights with the bank swizzle baked in: feature i of row n stored at
// chunk position p = (i & ~3) | ((i & 3) ^ (n & 3)); t=0 base_w,
// t=1..6 spline_w*scaler, t=7 zero. Rows n >= Nvalid are zero.
__global__ __launch_bounds__(256) void prep_w(
    const float* __restrict__ base_w, const float* __restrict__ spline_w,
    const float* __restrict__ scaler, short* __restrict__ Wp,
    int F, int Nvalid) {
  int i = blockIdx.x * 256 + threadIdx.x;
  int n = blockIdx.y;
  if (i >= F) return;
  s16x8 v;
#pragma unroll
  for (int k = 0; k < 8; ++k) v[k] = 0;
  if (n < Nvalid) {
    int idx = n * F + i;
    float sc = scaler[idx];
    v[0] = (short)f2bf(base_w[idx]);
#pragma unroll
    for (int k = 0; k < 6; ++k) v[1 + k] = (short)f2bf(spline_w[idx * 6 + k] * sc);
  }
  int p = (i & ~3) | ((i & 3) ^ (n & 3));
  *(s16x8*)&Wp[((size_t)n * F + p) * 8] = v;
}

// Fused-activation GEMM. BM=64, BN=256 per block, BK=32 (4 feats).
// 256 threads = 4 waves, all n-major: wave w covers cols [w*64, +64),
// NT = BN/64 = 4 n-tiles, acc[4][4] = 64 AGPR. Column origin c0 =
// blockIdx.y * BN (n-split); blockIdx.z = K-part -> Cp + z*pstride.
// 40KB LDS + <=128 regs/wave -> 4 blocks/CU (16 waves, 4/SIMD).
template <int BN>
__global__ __launch_bounds__(256, 4) void kan_gemm(
    const float* __restrict__ X, const short* __restrict__ W,
    float* __restrict__ Cp, int F, int span, long long pstride,
    int ldc, int ncols) {
  constexpr int NT = BN / 64;  // n-tiles per wave
  constexpr int IE = BN / 64;  // DMA issues per wave per step (16 rows each)
  __shared__ __align__(16) short As[2][64 * 32];
  __shared__ __align__(16) short Bs[2][BN * 32];

  const int t    = threadIdx.x;
  const int lane = t & 63;
  const int w    = t >> 6;
  const int m0   = blockIdx.x * 64;
  const int c0   = blockIdx.y * BN;   // column / W-row origin
  const int f0   = blockIdx.z * span;

  const int wcol = w * (BN / 4);
  const int mrow = lane & 15;
  const int q    = lane >> 4;
  const int qs   = (q ^ (mrow & 3)) * 8;

  // Single base offsets; per-tile +it*512 shorts (=1024B) folds into the
  // ds_read offset immediate (VGPR diet vs r8's offset arrays).
  const int a_lo = mrow * 32 + qs;
  const int b_lo = (wcol + mrow) * 32 + qs;

  // A staging: one activation per thread per step (64 rows x 4 features)
  const int sr = t >> 2, sj = t & 3;
  const float* xq = X + (size_t)(m0 + sr) * F + f0 + sj;
  const int aw = sr * 32 + ((sj ^ (sr & 3)) * 8);

  // B DMA: wave w covers Bs rows [w*BN/4, +BN/4), 16 rows per issue;
  // lane l -> (row l>>2, chunk l&3); LDS dest = uniform base + lane*16B.
  const int drow = c0 + wcol + (lane >> 2);
  const int dchk = lane & 3;
  const char* wg = (const char*)W + ((size_t)drow * F + f0 + dchk) * 16;
  const size_t gistr = (size_t)16 * F * 16;  // +16 W rows, bytes

  f32x4 acc[4][NT] = {};
  const int nsteps = span >> 2;

  // prologue: stage step 0; prefetch x for step 1 (2-step pipeline reg xA)
  float x0 = *xq;
#pragma unroll
  for (int e = 0; e < IE; ++e)
    dma16(wg + e * gistr, &Bs[0][(wcol + e * 16) * 32]);
  {
    uint4 av = kan_act8(x0);
    *(uint4*)&As[0][aw] = av;
  }
  float xA = (nsteps > 1) ? xq[4] : 0.0f;  // x for step 1's act
  __syncthreads();  // one-time full drain; loop barriers are counted

  for (int ks = 0; ks < nsteps; ++ks) {
    const int cb = ks & 1, nb = cb ^ 1;
    const bool more = (ks + 1 < nsteps);

    // x prefetch for step ks+2, issued at step top (2 steps of cover, and
    // always OLDER than the DMA batch awaited next step).
    float xB = 0.0f;
    if (ks + 2 < nsteps) xB = xq[(size_t)(ks + 2) * 4];

    if (more) {
#pragma unroll
      for (int e = 0; e < IE; ++e)
        dma16(wg + (size_t)(ks + 1) * 64 + e * gistr,
              &Bs[nb][(wcol + e * 16) * 32]);
      // Need step-ks DMAs (issued last step) landed. Allowed outstanding:
      // IE new DMAs + 1 x-load -> vmcnt(IE+1). Wave-local is sufficient:
      // this wave reads only rows it DMA'd itself.
      wait_vm<IE + 1>();
    } else {
      wait_vm<0>();  // final step: drain the last DMA batch
    }

    const short* Ac = As[cb];
    const short* Bc = Bs[cb];
    s16x8 af[4], bfr[NT];
#pragma unroll
    for (int it = 0; it < 4; ++it)
      af[it] = *(const s16x8*)(Ac + a_lo + it * (16 * 32));
#pragma unroll
    for (int jt = 0; jt < NT; ++jt)
      bfr[jt] = *(const s16x8*)(Bc + b_lo + jt * (16 * 32));
#pragma unroll
    for (int b = 0; b < NT; ++b)
#pragma unroll
      for (int a = 0; a < 4; ++a)
        acc[a][b] = __builtin_amdgcn_mfma_f32_16x16x32_bf16(
            af[a], bfr[b], acc[a][b], 0, 0, 0);

    if (more) {
      uint4 av = kan_act8(xA);
      *(uint4*)&As[nb][aw] = av;
      xA = xB;
    }
    // Only cross-wave dep through the barrier is the As ds_write: order it
    // with lgkmcnt(0); DMAs stay in flight across the barrier (T4).
    asm volatile("s_waitcnt lgkmcnt(0)" ::: "memory");
    __builtin_amdgcn_s_barrier();
  }

  // C/D layout: col = lane&15, row = quad*4 + reg (verified r1..r8)
  float* cpt = Cp + (size_t)blockIdx.z * (size_t)pstride;
#pragma unroll
  for (int a = 0; a < 4; ++a) {
#pragma unroll
    for (int b = 0; b < NT; ++b) {
      int col = c0 + wcol + b * 16 + mrow;
      if (col < ncols) {
#pragma unroll
        for (int r = 0; r < 4; ++r) {
          int row = m0 + a * 16 + (lane >> 4) * 4 + r;
          cpt[(size_t)row * ldc + col] = acc[a][b][r];
        }
      }
    }
  }
}

// h = LayerNorm(p0 + p1) over D=512, one wave per row.
__global__ __launch_bounds__(256) void ln_reduce(
    const float* __restrict__ p0, const float* __restrict__ p1,
    float* __restrict__ h, const float* __restrict__ gamma,
    const float* __restrict__ beta, int nparts) {
  int lane = threadIdx.x & 63;
  int wv   = threadIdx.x >> 6;
  int row  = blockIdx.x * 4 + wv;
  size_t base = (size_t)row * 512 + lane * 8;
  f32x4 v0 = *(const f32x4*)(p0 + base);
  f32x4 v1 = *(const f32x4*)(p0 + base + 4);
  if (nparts == 2) {
    f32x4 u0 = *(const f32x4*)(p1 + base);
    f32x4 u1 = *(const f32x4*)(p1 + base + 4);
#pragma unroll
    for (int k = 0; k < 4; ++k) { v0[k] += u0[k]; v1[k] += u1[k]; }
  }
  float s = 0.f, s2 = 0.f;
#pragma unroll
  for (int k = 0; k < 4; ++k) { s += v0[k] + v1[k]; s2 += v0[k]*v0[k] + v1[k]*v1[k]; }
#pragma unroll
  for (int m = 32; m >= 1; m >>= 1) {
    s  += __shfl_xor(s,  m, 64);
    s2 += __shfl_xor(s2, m, 64);
  }
  float mean = s * (1.0f / 512.0f);
  float var  = s2 * (1.0f / 512.0f) - mean * mean;
  float rstd = rsqrtf(var + 1e-5f);
  const f32x4 g0 = *(const f32x4*)(gamma + lane * 8);
  const f32x4 g1 = *(const f32x4*)(gamma + lane * 8 + 4);
  const f32x4 be0 = *(const f32x4*)(beta + lane * 8);
  const f32x4 be1 = *(const f32x4*)(beta + lane * 8 + 4);
#pragma unroll
  for (int k = 0; k < 4; ++k) {
    v0[k] = (v0[k] - mean) * rstd * g0[k] + be0[k];
    v1[k] = (v1[k] - mean) * rstd * g1[k] + be1[k];
  }
  *(f32x4*)(h + base) = v0;
  *(f32x4*)(h + base + 4) = v1;
}

// out[b][c<229] = p0[b][c] (+ p1[b][c]) from 256-wide padded partials.
__global__ __launch_bounds__(256) void out_reduce(
    const float* __restrict__ p0, const float* __restrict__ p1,
    float* __restrict__ out, int nparts) {
  int idx = blockIdx.x * 256 + threadIdx.x;
  int row = idx >> 8;
  int c   = idx & 255;
  float v = p0[idx];
  if (nparts == 2) v += p1[idx];
  if (c < 229) out[(size_t)row * 229 + c] = v;
}

extern "C" void kernel_launch(void* const* d_in, const int* in_sizes, int n_in,
                              void* d_out, int out_size, void* d_ws, size_t ws_size,
                              hipStream_t stream) {
  const float* x         = (const float*)d_in[0];
  const float* base_w1   = (const float*)d_in[1];
  const float* spline_w1 = (const float*)d_in[2];
  const float* scaler1   = (const float*)d_in[3];
  const float* ln_gamma  = (const float*)d_in[4];
  const float* ln_beta   = (const float*)d_in[5];
  const float* base_w2   = (const float*)d_in[6];
  const float* spline_w2 = (const float*)d_in[7];
  const float* scaler2   = (const float*)d_in[8];
  float* out = (float*)d_out;

  const int B = 16384, D_IN = 1280, D_HID = 512, D_OUT = 229;

  // ws layout: W1p | W2p | h | p0 | p1   (~113 MB with parts=2)
  const size_t szW1 = (size_t)D_HID * D_IN * 8 * 2;   // 10,485,760
  const size_t szW2 = (size_t)256 * D_HID * 8 * 2;    //  2,097,152
  const size_t szH  = (size_t)B * D_HID * 4;          // 33,554,432
  const size_t szP  = (size_t)B * 512 * 4;            // 33,554,432 slot
  char* ws = (char*)d_ws;
  short* W1p = (short*)ws;
  short* W2p = (short*)(ws + szW1);
  float* h   = (float*)(ws + szW1 + szW2);
  float* p0  = (float*)(ws + szW1 + szW2 + szH);
  float* p1  = (float*)(ws + szW1 + szW2 + szH + szP);

  const int parts = (ws_size >= szW1 + szW2 + szH + 2 * szP) ? 2 : 1;
  const long long pstride = (long long)(szP / 4);  // elements = slot size

  prep_w<<<dim3(D_IN / 256, D_HID), 256, 0, stream>>>(
      base_w1, spline_w1, scaler1, W1p, D_IN, D_HID);
  prep_w<<<dim3(D_HID / 256, 256), 256, 0, stream>>>(
      base_w2, spline_w2, scaler2, W2p, D_HID, D_OUT);

  // layer 1: (16384 x 1280) -> split-K + n-split(2): BN=256 blocks,
  // partials (16384 x 512) x parts
  kan_gemm<256><<<dim3(B / 64, D_HID / 256, parts), 256, 0, stream>>>(
      x, W1p, p0, D_IN, D_IN / parts, pstride, D_HID, D_HID);

  ln_reduce<<<dim3(B / 4), 256, 0, stream>>>(p0, p1, h, ln_gamma, ln_beta, parts);

  // layer 2: (16384 x 512) -> split-K partials (16384 x 256) x parts
  kan_gemm<256><<<dim3(B / 64, 1, parts), 256, 0, stream>>>(
      h, W2p, p0, D_HID, D_HID / parts, pstride, 256, 256);

  out_reduce<<<dim3(B * 256 / 256), 256, 0, stream>>>(p0, p1, out, parts);
}

// Round 3
// 456.583 us; speedup vs baseline: 1.0224x; 1.0224x over previous
//
#include <hip/hip_runtime.h>

// ---------------------------------------------------------------------------
// KAN 2-layer forward, round 10.
// r8: counted-vmcnt = null. r9: 2x occupancy = slightly worse (wall/step
// 3946->4260, MfmaUtil flat 27-28%). No pipe >50% across three structures ->
// limiter is per-step instruction count + serialization, not waves/barriers.
// r10 attacks per-FLOP instruction cost at constant geometry cost:
//  - mfma_f32_32x32x16_bf16: half the MFMA instrs, +20% pipe rate
//    (C/D layout per guide m74/m101: col=lane&31, row=(reg&3)+8*(reg>>2)
//    +4*(lane>>5); A/B frag: lane holds row l&31 / k=(l>>5)*8+j).
//  - BN=512, 8 waves, BM=64, 72KB LDS (r7-proven 2 blocks/CU = 4 waves/SIMD;
//    r9 showed exact-160KB fit loses a block). No n-split -> act NOT
//    duplicated (act on waves 0-3 only; x-loads halve). B stays wave-private
//    (wave w = cols [w*64,+64)) so counted-vmcnt stays valid.
//  - swizzle upgrade: chunk ^= (row>>1)&3 -> frag reads 8-way -> 4-way floor.
// ---------------------------------------------------------------------------

typedef short s16x8 __attribute__((ext_vector_type(8)));  // 8 bf16 = 4 VGPRs
typedef float f32x4 __attribute__((ext_vector_type(4)));
typedef float f32x16 __attribute__((ext_vector_type(16)));

__device__ __forceinline__ void dma16(const void* g, void* l) {
  __builtin_amdgcn_global_load_lds(
      (const __attribute__((address_space(1))) unsigned int*)g,
      (__attribute__((address_space(3))) unsigned int*)l, 16, 0, 0);
}

template <int N>
__device__ __forceinline__ void wait_vm() {
  if constexpr (N == 0)      asm volatile("s_waitcnt vmcnt(0)" ::: "memory");
  else if constexpr (N == 4) asm volatile("s_waitcnt vmcnt(4)" ::: "memory");
  else if constexpr (N == 5) asm volatile("s_waitcnt vmcnt(5)" ::: "memory");
  else static_assert(N == 0, "unsupported vmcnt");
}

__device__ __forceinline__ unsigned pk2(float lo, float hi) {
  unsigned a = __float_as_uint(lo), b = __float_as_uint(hi);
  a = a + 0x7fffu + ((a >> 16) & 1u);
  b = b + 0x7fffu + ((b >> 16) & 1u);
  return __builtin_amdgcn_perm(b, a, 0x07060302u);  // {b.hi16, a.hi16}
}

__device__ __forceinline__ unsigned short f2bf(float f) {
  unsigned u = __float_as_uint(f);
  unsigned r = u + 0x7fffu + ((u >> 16) & 1u);
  return (unsigned short)(r >> 16);
}

// silu + 6 cubic B-spline bases (uniform extended grid, u = 1.5x+4.5, knots
// u=0..9; recursion ref-verified r1..r9). Packed bf16x8 [silu,b3_0..5,0].
__device__ __forceinline__ uint4 kan_act8(float x) {
  float e = __expf(-x);
  float s = x * __builtin_amdgcn_rcpf(1.0f + e);
  float u = fmaf(x, 1.5f, 4.5f);
  float d[10];
#pragma unroll
  for (int j = 0; j < 10; ++j) d[j] = u - (float)j;
  float b1[8];
#pragma unroll
  for (int j = 0; j < 8; ++j) b1[j] = fmaxf(0.0f, 1.0f - fabsf(d[j + 1]));
  float B2[7];
#pragma unroll
  for (int j = 0; j < 7; ++j) B2[j] = d[j] * b1[j] - d[j + 3] * b1[j + 1];
  float b3[6];
#pragma unroll
  for (int j = 0; j < 6; ++j)
    b3[j] = (d[j] * B2[j] - d[j + 4] * B2[j + 1]) * (1.0f / 6.0f);
  uint4 r;
  r.x = pk2(s, b3[0]);
  r.y = pk2(b3[1], b3[2]);
  r.z = pk2(b3[3], b3[4]);
  r.w = pk2(b3[5], 0.0f);
  return r;
}

// Pack weights with the bank swizzle baked in: feature i of row n stored at
// chunk position p = (i & ~3) | ((i & 3) ^ ((n >> 1) & 3)); t=0 base_w,
// t=1..6 spline_w*scaler, t=7 zero. Rows n >= Nvalid are zero.
// (r10: swizzle key row&3 -> (row>>1)&3, matching the 4-way-floor read swz.)
__global__ __launch_bounds__(256) void prep_w(
    const float* __restrict__ base_w, const float* __restrict__ spline_w,
    const float* __restrict__ scaler, short* __restrict__ Wp,
    int F, int Nvalid) {
  int i = blockIdx.x * 256 + threadIdx.x;
  int n = blockIdx.y;
  if (i >= F) return;
  s16x8 v;
#pragma unroll
  for (int k = 0; k < 8; ++k) v[k] = 0;
  if (n < Nvalid) {
    int idx = n * F + i;
    float sc = scaler[idx];
    v[0] = (short)f2bf(base_w[idx]);
#pragma unroll
    for (int k = 0; k < 6; ++k) v[1 + k] = (short)f2bf(spline_w[idx * 6 + k] * sc);
  }
  int p = (i & ~3) | ((i & 3) ^ ((n >> 1) & 3));
  *(s16x8*)&Wp[((size_t)n * F + p) * 8] = v;
}

// Fused-activation GEMM, 32x32x16 MFMA. BM=64, BN in {512,256}, BK=32.
// THREADS = BN, WAVES = BN/64; wave w owns cols [w*64,+64) (n-major,
// wave-private B -> counted vmcnt valid). Per wave: 2 m-tiles x 2 n-tiles of
// 32x32, acc[2][2] f32x16 = 64 regs. Act staged to LDS by threads < 256
// (waves 0-3), read by all waves; barrier orders only the A ds_write.
template <int BN>
__global__ __launch_bounds__(BN, 4) void kan_gemm(
    const float* __restrict__ X, const short* __restrict__ W,
    float* __restrict__ Cp, int F, int span, long long pstride,
    int ldc, int ncols) {
  __shared__ __align__(16) short As[2][64 * 32];
  __shared__ __align__(16) short Bs[2][BN * 32];

  const int t    = threadIdx.x;
  const int lane = t & 63;
  const int w    = t >> 6;
  const int m0   = blockIdx.x * 64;
  const int f0   = blockIdx.z * span;

  const int wcol = w * 64;
  const int r5   = lane & 31;        // row-in-tile
  const int hi   = lane >> 5;        // k-half selector
  const int e2   = (lane >> 1) & 3;  // (row>>1)&3 swizzle key

  // frag read bases (shorts); physical chunk = (kk*2+hi) ^ e2
  const int a_base = r5 * 32;
  const int b_base = (wcol + r5) * 32;
  const int koff0  = ((0 + hi) ^ e2) * 8;   // kk=0
  const int koff1  = ((2 + hi) ^ e2) * 8;   // kk=1

  // A staging: threads < 256 (waves 0-3): one act per step (64 rows x 4 feat)
  const int sr = t >> 2, sj = t & 3;
  const float* xq = X + (size_t)(m0 + sr) * F + f0 + sj;
  const int aw = sr * 32 + ((sj ^ ((sr >> 1) & 3)) * 8);
  const bool actor = (t < 256);

  // B DMA: wave w stages Bs rows [wcol, wcol+64), 4 issues x 16 rows;
  // lane l -> (row l>>2, chunk l&3); LDS dest = uniform base + lane*16B.
  const int drow = wcol + (lane >> 2);
  const int dchk = lane & 3;
  const char* wg = (const char*)W + ((size_t)drow * F + f0 + dchk) * 16;
  const size_t gistr = (size_t)16 * F * 16;  // +16 W rows, bytes

  f32x16 acc[2][2] = {};
  const int nsteps = span >> 2;

  // prologue: stage step 0; prefetch x for step 1
  float x0 = actor ? *xq : 0.0f;
#pragma unroll
  for (int e = 0; e < 4; ++e)
    dma16(wg + e * gistr, &Bs[0][(wcol + e * 16) * 32]);
  if (actor) {
    uint4 av = kan_act8(x0);
    *(uint4*)&As[0][aw] = av;
  }
  float xA = (actor && nsteps > 1) ? xq[4] : 0.0f;
  __syncthreads();  // one-time full drain; loop barriers are counted

  for (int ks = 0; ks < nsteps; ++ks) {
    const int cb = ks & 1, nb = cb ^ 1;
    const bool more = (ks + 1 < nsteps);

    // x prefetch for step ks+2 (clamped so VMEM count/iter is constant)
    float xB = 0.0f;
    if (actor) {
      int pf = ks + 2 < nsteps ? ks + 2 : nsteps - 1;
      xB = xq[(size_t)pf * 4];
    }

    if (more) {
#pragma unroll
      for (int e = 0; e < 4; ++e)
        dma16(wg + (size_t)(ks + 1) * 64 + e * gistr,
              &Bs[nb][(wcol + e * 16) * 32]);
      // Drain last iter's batch (4 dma [+1 x for actors]); allow this
      // iter's in flight. Wave-local: wave reads only rows it DMA'd.
      if (actor) wait_vm<5>(); else wait_vm<4>();
    } else {
      wait_vm<0>();  // final step: drain the last DMA batch
    }

    const short* Ac = As[cb];
    const short* Bc = Bs[cb];
#pragma unroll
    for (int kk = 0; kk < 2; ++kk) {
      const int ko = kk ? koff1 : koff0;
      s16x8 af0 = *(const s16x8*)(Ac + a_base + ko);
      s16x8 af1 = *(const s16x8*)(Ac + a_base + 1024 + ko);
      s16x8 bf0 = *(const s16x8*)(Bc + b_base + ko);
      s16x8 bf1 = *(const s16x8*)(Bc + b_base + 1024 + ko);
      __builtin_amdgcn_s_setprio(1);
      acc[0][0] = __builtin_amdgcn_mfma_f32_32x32x16_bf16(af0, bf0, acc[0][0], 0, 0, 0);
      acc[0][1] = __builtin_amdgcn_mfma_f32_32x32x16_bf16(af0, bf1, acc[0][1], 0, 0, 0);
      acc[1][0] = __builtin_amdgcn_mfma_f32_32x32x16_bf16(af1, bf0, acc[1][0], 0, 0, 0);
      acc[1][1] = __builtin_amdgcn_mfma_f32_32x32x16_bf16(af1, bf1, acc[1][1], 0, 0, 0);
      __builtin_amdgcn_s_setprio(0);
    }

    if (more && actor) {
      uint4 av = kan_act8(xA);
      *(uint4*)&As[nb][aw] = av;
      xA = xB;
    }
    // Only cross-wave dep through the barrier is the As ds_write: order it
    // with lgkmcnt(0); DMAs stay in flight across the barrier (T4).
    asm volatile("s_waitcnt lgkmcnt(0)" ::: "memory");
    __builtin_amdgcn_s_barrier();
  }

  // C/D layout (32x32): col = lane&31, row = (reg&3) + 8*(reg>>2) + 4*hi
  float* cpt = Cp + (size_t)blockIdx.z * (size_t)pstride;
#pragma unroll
  for (int mt = 0; mt < 2; ++mt) {
#pragma unroll
    for (int nt = 0; nt < 2; ++nt) {
      int col = wcol + nt * 32 + r5;
      if (col < ncols) {
#pragma unroll
        for (int reg = 0; reg < 16; ++reg) {
          int row = m0 + mt * 32 + (reg & 3) + 8 * (reg >> 2) + 4 * hi;
          cpt[(size_t)row * ldc + col] = acc[mt][nt][reg];
        }
      }
    }
  }
}

// h = LayerNorm(p0 + p1) over D=512, one wave per row.
__global__ __launch_bounds__(256) void ln_reduce(
    const float* __restrict__ p0, const float* __restrict__ p1,
    float* __restrict__ h, const float* __restrict__ gamma,
    const float* __restrict__ beta, int nparts) {
  int lane = threadIdx.x & 63;
  int wv   = threadIdx.x >> 6;
  int row  = blockIdx.x * 4 + wv;
  size_t base = (size_t)row * 512 + lane * 8;
  f32x4 v0 = *(const f32x4*)(p0 + base);
  f32x4 v1 = *(const f32x4*)(p0 + base + 4);
  if (nparts == 2) {
    f32x4 u0 = *(const f32x4*)(p1 + base);
    f32x4 u1 = *(const f32x4*)(p1 + base + 4);
#pragma unroll
    for (int k = 0; k < 4; ++k) { v0[k] += u0[k]; v1[k] += u1[k]; }
  }
  float s = 0.f, s2 = 0.f;
#pragma unroll
  for (int k = 0; k < 4; ++k) { s += v0[k] + v1[k]; s2 += v0[k]*v0[k] + v1[k]*v1[k]; }
#pragma unroll
  for (int m = 32; m >= 1; m >>= 1) {
    s  += __shfl_xor(s,  m, 64);
    s2 += __shfl_xor(s2, m, 64);
  }
  float mean = s * (1.0f / 512.0f);
  float var  = s2 * (1.0f / 512.0f) - mean * mean;
  float rstd = rsqrtf(var + 1e-5f);
  const f32x4 g0 = *(const f32x4*)(gamma + lane * 8);
  const f32x4 g1 = *(const f32x4*)(gamma + lane * 8 + 4);
  const f32x4 be0 = *(const f32x4*)(beta + lane * 8);
  const f32x4 be1 = *(const f32x4*)(beta + lane * 8 + 4);
#pragma unroll
  for (int k = 0; k < 4; ++k) {
    v0[k] = (v0[k] - mean) * rstd * g0[k] + be0[k];
    v1[k] = (v1[k] - mean) * rstd * g1[k] + be1[k];
  }
  *(f32x4*)(h + base) = v0;
  *(f32x4*)(h + base + 4) = v1;
}

// out[b][c<229] = p0[b][c] (+ p1[b][c]) from 256-wide padded partials.
__global__ __launch_bounds__(256) void out_reduce(
    const float* __restrict__ p0, const float* __restrict__ p1,
    float* __restrict__ out, int nparts) {
  int idx = blockIdx.x * 256 + threadIdx.x;
  int row = idx >> 8;
  int c   = idx & 255;
  float v = p0[idx];
  if (nparts == 2) v += p1[idx];
  if (c < 229) out[(size_t)row * 229 + c] = v;
}

extern "C" void kernel_launch(void* const* d_in, const int* in_sizes, int n_in,
                              void* d_out, int out_size, void* d_ws, size_t ws_size,
                              hipStream_t stream) {
  const float* x         = (const float*)d_in[0];
  const float* base_w1   = (const float*)d_in[1];
  const float* spline_w1 = (const float*)d_in[2];
  const float* scaler1   = (const float*)d_in[3];
  const float* ln_gamma  = (const float*)d_in[4];
  const float* ln_beta   = (const float*)d_in[5];
  const float* base_w2   = (const float*)d_in[6];
  const float* spline_w2 = (const float*)d_in[7];
  const float* scaler2   = (const float*)d_in[8];
  float* out = (float*)d_out;

  const int B = 16384, D_IN = 1280, D_HID = 512, D_OUT = 229;

  // ws layout: W1p | W2p | h | p0 | p1   (~113 MB with parts=2)
  const size_t szW1 = (size_t)D_HID * D_IN * 8 * 2;   // 10,485,760
  const size_t szW2 = (size_t)256 * D_HID * 8 * 2;    //  2,097,152
  const size_t szH  = (size_t)B * D_HID * 4;          // 33,554,432
  const size_t szP  = (size_t)B * 512 * 4;            // 33,554,432 slot
  char* ws = (char*)d_ws;
  short* W1p = (short*)ws;
  short* W2p = (short*)(ws + szW1);
  float* h   = (float*)(ws + szW1 + szW2);
  float* p0  = (float*)(ws + szW1 + szW2 + szH);
  float* p1  = (float*)(ws + szW1 + szW2 + szH + szP);

  const int parts = (ws_size >= szW1 + szW2 + szH + 2 * szP) ? 2 : 1;
  const long long pstride = (long long)(szP / 4);  // elements = slot size

  prep_w<<<dim3(D_IN / 256, D_HID), 256, 0, stream>>>(
      base_w1, spline_w1, scaler1, W1p, D_IN, D_HID);
  prep_w<<<dim3(D_HID / 256, 256), 256, 0, stream>>>(
      base_w2, spline_w2, scaler2, W2p, D_HID, D_OUT);

  // layer 1: (16384 x 1280) -> split-K partials (16384 x 512) x parts
  // BN=512, 512 threads, no n-split (act computed once).
  kan_gemm<512><<<dim3(B / 64, 1, parts), 512, 0, stream>>>(
      x, W1p, p0, D_IN, D_IN / parts, pstride, D_HID, D_HID);

  ln_reduce<<<dim3(B / 4), 256, 0, stream>>>(p0, p1, h, ln_gamma, ln_beta, parts);

  // layer 2: (16384 x 512) -> split-K partials (16384 x 256) x parts
  kan_gemm<256><<<dim3(B / 64, 1, parts), 256, 0, stream>>>(
      h, W2p, p0, D_HID, D_HID / parts, pstride, 256, 256);

  out_reduce<<<dim3(B * 256 / 256), 256, 0, stream>>>(p0, p1, out, parts);
}